// Round 1
// baseline (357.015 us; speedup 1.0000x reference)
//
#include <hip/hip_runtime.h>

// Problem constants: B=4, N=4096 -> nPoints=16384
#define KN 32                 // neighbors per point
#define FF 64                 // input feature dim
#define CC 256                // H*D channels (H=16 heads, D=16)
#define KV_STRIDE 260         // pad 256->260: all kvS phases <=2-way bank aliased (validated R2)
#define VOFF (KN * KV_STRIDE) // V offset inside kvS (floats)
#define NITER 16              // points per block
#define QSTRIDE 264           // ushorts per qAll row (264*2B = 132 dwords, !=0 mod 32)
#define WSTRIDE 33            // wS stride: head h reads bank (h+k)%32 -> conflict-free

// Faithful-reshape semantics (validated R1/R2):
//   K[b,n,h,k,d] = K_proj[b,n, j=2h+(k>>4), ch=(k&15)*16+d];  V likewise.
//   Q[b,n,h,0,d] = Q_proj[b,n, h*16+d].

typedef __attribute__((ext_vector_type(8)))  short bf16x8;   // 8 bf16 = 4 VGPRs
typedef __attribute__((ext_vector_type(16))) float f32x16;   // 32x32 MFMA acc
typedef __attribute__((ext_vector_type(4)))  float f32x4;    // 16x16 MFMA acc

__device__ inline unsigned short f2bf(float f) {             // fp32->bf16 RNE (epilogue only)
    union { float f; unsigned u; } v; v.f = f;
    unsigned u = v.u + 0x7fffu + ((v.u >> 16) & 1u);
    return (unsigned short)(u >> 16);
}
// HW packed fp32->bf16 RNE: 1 instr per pair vs ~8 for the manual sequence.
__device__ inline unsigned cvt_pk_bf16(float a, float b) {
    unsigned r;
    asm("v_cvt_pk_bf16_f32 %0, %1, %2" : "=v"(r) : "v"(a), "v"(b));
    return r;
}
__device__ inline bf16x8 pack8(float4 a, float4 b) {
    union { bf16x8 v; unsigned u[4]; } r;
    r.u[0] = cvt_pk_bf16(a.x, a.y);  r.u[1] = cvt_pk_bf16(a.z, a.w);
    r.u[2] = cvt_pk_bf16(b.x, b.y);  r.u[3] = cvt_pk_bf16(b.z, b.w);
    return r.v;
}

// Single fused kernel. Block = 256 threads (4 waves), NITER points per block.
// Prologue: Q-projection for all 16 points via 16x16x32 MFMA -> qAll (bf16 LDS).
// Main loop: K/V projection via 32x32x16 MFMA (A-row register-prefetched, bias
// pre-loaded into the accumulator), then validated attention wiring from LDS.
__global__ __launch_bounds__(256, 2)
void attn_one(const float* __restrict__ inp,
              const float* __restrict__ query,
              const float* __restrict__ Wq,
              const float* __restrict__ bq,
              const float* __restrict__ Wk,
              const float* __restrict__ bk,
              const float* __restrict__ Wv,
              const float* __restrict__ bv,
              float* __restrict__ out, int nPoints)
{
    __shared__ float kvS[2 * KN * KV_STRIDE];        // 66.5 KB: K then V (fp32)
    __shared__ unsigned short qAllS[NITER * QSTRIDE];// 8.4 KB: pre-scaled Q, bf16
    __shared__ float wS[16 * WSTRIDE];               // softmax weights (intra-wave)

    const int tid  = threadIdx.x;
    const int wave = tid >> 6;
    const int L    = tid & 63;
    const int Lm   = L & 31;       // M/N index inside the 32x32 tile
    const int Lh   = L >> 5;       // k-half selector (32x32x16)
    const int h    = tid >> 4;     // attention head 0..15
    const int d    = tid & 15;     // dim within head
    const int bid  = blockIdx.x;
    const int grid = gridDim.x;

    // ---- stage this block's 16 query rows into kvS scratch (freed later) ----
    float* qIn = kvS;              // 16 rows x 68 floats (pad 64->68)
    {
        const int i  = tid >> 4;           // point slot 0..15
        const int f4 = (tid & 15) * 4;
        const int p  = bid + i * grid;
        if (p < nPoints)
            *(float4*)(qIn + i * 68 + f4) =
                *(const float4*)(query + (size_t)p * FF + f4);
    }

    // ---- prefetch first point's A-row into registers ----
    float4 pf[8];
    {
        const float* arow = inp + (size_t)bid * (KN * FF) + Lm * FF + Lh * 8;
#pragma unroll
        for (int s = 0; s < 4; ++s) {
            pf[2 * s]     = *(const float4*)(arow + s * 16);
            pf[2 * s + 1] = *(const float4*)(arow + s * 16 + 4);
        }
    }

    // ---- Wk/Wv B fragments + bias (validated R2 layout) ----
    // B[k][n]: lane holds k = s*16 + Lh*8 + j, n = chunk*32 + Lm
    bf16x8 Bf[4][4];   // [tile: K0,K1,V0,V1][kstep]
    float  bias[4];
#pragma unroll
    for (int t = 0; t < 4; ++t) {
        const float* W  = (t < 2) ? Wk : Wv;
        const float* bb = (t < 2) ? bk : bv;
        const int ch    = (2 * wave + (t & 1)) * 32 + Lm;
        bias[t] = bb[ch];
#pragma unroll
        for (int s = 0; s < 4; ++s) {
            union { bf16x8 v; unsigned u[4]; } r;
#pragma unroll
            for (int jj = 0; jj < 4; ++jj) {
                const int f = s * 16 + Lh * 8 + 2 * jj;
                r.u[jj] = cvt_pk_bf16(W[(size_t)f * CC + ch], W[(size_t)(f + 1) * CC + ch]);
            }
            Bf[t][s] = r.v;
        }
    }

    // ---- Wq B fragments: 4 N-tiles of 16 per wave, K=64 in 2 steps ----
    // 16x16x32 layouts (HW-verified): A[m=lane&15][k=(lane>>4)*8+j],
    // B[k=(lane>>4)*8+j][n=lane&15], C/D col=lane&15 row=(lane>>4)*4+reg.
    const int nq = L & 15;
    const int kq = (L >> 4) * 8;
    bf16x8 Bq[4][2];
    float  bqv[4];
#pragma unroll
    for (int tt = 0; tt < 4; ++tt) {
        const int ch = wave * 64 + tt * 16 + nq;
        bqv[tt] = bq[ch];
#pragma unroll
        for (int s = 0; s < 2; ++s) {
            union { bf16x8 v; unsigned u[4]; } r;
#pragma unroll
            for (int jj = 0; jj < 4; ++jj) {
                const int f = s * 32 + kq + 2 * jj;
                r.u[jj] = cvt_pk_bf16(Wq[(size_t)f * CC + ch], Wq[(size_t)(f + 1) * CC + ch]);
            }
            Bq[tt][s] = r.v;
        }
    }

    __syncthreads();   // qIn staged

    // ---- Q-projection MFMA: M=16 points, N=256 channels, K=64 ----
    {
        bf16x8 Aq[2];
        const int im = L & 15;
#pragma unroll
        for (int s = 0; s < 2; ++s) {
            const float* qr = qIn + im * 68 + s * 32 + kq;
            Aq[s] = pack8(*(const float4*)qr, *(const float4*)(qr + 4));
        }
#pragma unroll
        for (int tt = 0; tt < 4; ++tt) {
            // bias pre-loaded into the accumulator (C carries it through MFMA)
            f32x4 qa = {bqv[tt], bqv[tt], bqv[tt], bqv[tt]};
#pragma unroll
            for (int s = 0; s < 2; ++s)
                qa = __builtin_amdgcn_mfma_f32_16x16x32_bf16(Aq[s], Bq[tt][s], qa, 0, 0, 0);
            const int ch = wave * 64 + tt * 16 + nq;
#pragma unroll
            for (int r = 0; r < 4; ++r) {
                const int ip = (L >> 4) * 4 + r;    // point slot 0..15
                qAllS[ip * QSTRIDE + ch] = f2bf(qa[r] * 0.25f);
            }
        }
    }
    __syncthreads();   // qAll ready; kvS scratch free

    // ================= main loop over this block's points =================
    for (int it = 0, p = bid; p < nPoints; ++it, p += grid) {
        // pack A fragments from prefetched registers (HW packed cvt: 16 instrs)
        bf16x8 Af[4];
#pragma unroll
        for (int s = 0; s < 4; ++s) Af[s] = pack8(pf[2 * s], pf[2 * s + 1]);

        // prefetch next point's A-row (latency hidden by MFMA + attention)
        const int pn = p + grid;
        if (pn < nPoints) {
            const float* arow = inp + (size_t)pn * (KN * FF) + Lm * FF + Lh * 8;
#pragma unroll
            for (int s = 0; s < 4; ++s) {
                pf[2 * s]     = *(const float4*)(arow + s * 16);
                pf[2 * s + 1] = *(const float4*)(arow + s * 16 + 4);
            }
        }

        // K/V projection MFMAs — bias broadcast into the accumulator init:
        // every acc element of a lane shares one output column => one value.
        f32x16 acc[4];
#pragma unroll
        for (int t = 0; t < 4; ++t)
#pragma unroll
            for (int r = 0; r < 16; ++r) acc[t][r] = bias[t];
#pragma unroll
        for (int s = 0; s < 4; ++s)
#pragma unroll
            for (int t = 0; t < 4; ++t)
                acc[t] = __builtin_amdgcn_mfma_f32_32x32x16_bf16(Af[s], Bf[t][s], acc[t], 0, 0, 0);

        // C writeback -> kvS.  C: col=chunk*32+Lm, row=(r&3)+8*(r>>2)+4*Lh
#pragma unroll
        for (int t = 0; t < 4; ++t) {
            float* dstbase = kvS + ((t < 2) ? 0 : VOFF);
            const int col  = (2 * wave + (t & 1)) * 32 + Lm;
#pragma unroll
            for (int r = 0; r < 16; ++r) {
                const int jrow = (r & 3) + 8 * (r >> 2) + 4 * Lh;
                dstbase[jrow * KV_STRIDE + col] = acc[t][r];
            }
        }
        __syncthreads();   // kvS ready

        // ---- logits: lane (h,d) owns k = 2d, 2d+1 (same neighbor row) ----
        const unsigned short* qrow = qAllS + it * QSTRIDE + h * 16;
        const int j0  = 2 * h + (d >> 3);
        const int g16 = ((2 * d) & 15) * 16;
        const float* Krow = kvS + j0 * KV_STRIDE + g16;
        float l0 = 0.f, l1 = 0.f;
#pragma unroll
        for (int i = 0; i < 16; ++i) {
            const int dp = (d + i) & 15;                 // rotation: banks spread
            const float qv = __uint_as_float((unsigned)qrow[dp] << 16);
            l0 = fmaf(qv, Krow[dp],      l0);
            l1 = fmaf(qv, Krow[16 + dp], l1);
        }

        // ---- softmax across the head's 16 lanes ----
        float m = fmaxf(l0, l1);
        m = fmaxf(m, __shfl_xor(m, 1));
        m = fmaxf(m, __shfl_xor(m, 2));
        m = fmaxf(m, __shfl_xor(m, 4));
        m = fmaxf(m, __shfl_xor(m, 8));
        float e0 = __expf(l0 - m), e1 = __expf(l1 - m);
        float s2 = e0 + e1;
        s2 += __shfl_xor(s2, 1);
        s2 += __shfl_xor(s2, 2);
        s2 += __shfl_xor(s2, 4);
        s2 += __shfl_xor(s2, 8);
        const float inv = 1.0f / s2;
        wS[h * WSTRIDE + 2 * d]     = e0 * inv;   // intra-wave producer/consumer
        wS[h * WSTRIDE + 2 * d + 1] = e1 * inv;
        __builtin_amdgcn_wave_barrier();

        // ---- output: out[h*16+d] = sum_k w[k] * V[j(k), (k&15)*16+d] ----
        float o = 0.f;
        const float* Vbase = kvS + VOFF;
#pragma unroll
        for (int k = 0; k < KN; ++k) {
            const int jk = 2 * h + (k >> 4);
            o = fmaf(wS[h * WSTRIDE + k], Vbase[jk * KV_STRIDE + (k & 15) * 16 + d], o);
        }
        out[(size_t)p * CC + tid] = o;

        __syncthreads();   // kvS fully consumed before next point overwrites
    }
}

extern "C" void kernel_launch(void* const* d_in, const int* in_sizes, int n_in,
                              void* d_out, int out_size, void* d_ws, size_t ws_size,
                              hipStream_t stream) {
    const float* inp   = (const float*)d_in[0];
    const float* query = (const float*)d_in[1];
    const float* Wq    = (const float*)d_in[2];
    const float* bq    = (const float*)d_in[3];
    const float* Wk    = (const float*)d_in[4];
    const float* bk    = (const float*)d_in[5];
    const float* Wv    = (const float*)d_in[6];
    const float* bv    = (const float*)d_in[7];
    float* out = (float*)d_out;

    const int nPoints = in_sizes[0] / (KN * FF);          // B*N = 16384
    const int grid    = (nPoints + NITER - 1) / NITER;    // 1024

    attn_one<<<grid, 256, 0, stream>>>(inp, query, Wq, bq, Wk, bk, Wv, bv,
                                       out, nPoints);
}